// Round 2
// baseline (73.955 us; speedup 1.0000x reference)
//
#include <hip/hip_runtime.h>
#include <stdint.h>

typedef __attribute__((ext_vector_type(8))) short short8;
typedef __attribute__((ext_vector_type(4))) float f32x4;

#define SEQ 256
#define NH 8

// round-to-nearest-away bf16 pair pack: (hi<<16)|lo
__device__ __forceinline__ uint32_t bf16pack2(float lo, float hi) {
  uint32_t a = (__builtin_bit_cast(uint32_t, lo) + 0x8000u) >> 16;
  uint32_t b = (__builtin_bit_cast(uint32_t, hi) + 0x8000u) & 0xFFFF0000u;
  return b | a;
}

// ---------------------------------------------------------------------------
// Kernel 1: build layer-1 partial-sum tables (pre-ReLU).
//   Apos[f][h][k]  = sum_p  e_pos[f,h,p]  * w1[p      ][k][h]   (f in [0,512))
//   Ai[b][m][h][k] = sum_j  e_bi[bs,h,j]  * w1[32+j][k][h] + e_ci[cs,h,j]*w1[64+j][k][h]
//   Aj[b][n][h][k] = sum_j  e_bj[bs,h,j]  * w1[48+j][k][h] + e_cj[cs,h,j]*w1[80+j][k][h]
// One thread computes a k-quad (4 outputs). 163840 threads = 640 blocks.
// ---------------------------------------------------------------------------
__global__ __launch_bounds__(256) void build_tables(
    const int* __restrict__ bseq, const int* __restrict__ cseq,
    const float* __restrict__ epos, const float* __restrict__ ebi,
    const float* __restrict__ ebj, const float* __restrict__ eci,
    const float* __restrict__ ecj, const float* __restrict__ w1,
    float* __restrict__ Apos, float* __restrict__ Ai, float* __restrict__ Aj) {
  int id = blockIdx.x * 256 + threadIdx.x;
  float a0 = 0.f, a1 = 0.f, a2 = 0.f, a3 = 0.f;
  if (id < 32768) {                       // pos table: 512*8*8 quads
    int kq = id & 7, h = (id >> 3) & 7, f = id >> 6;
    const float* x = epos + (f * NH + h) * 32;
    const float* wb = w1 + kq * 32 + h;   // w1[p*256 + (kq*4+i)*8 + h]
#pragma unroll
    for (int p = 0; p < 32; ++p) {
      float xv = x[p];
      const float* wr = wb + p * 256;
      a0 += xv * wr[0]; a1 += xv * wr[8]; a2 += xv * wr[16]; a3 += xv * wr[24];
    }
    f32x4 v = {a0, a1, a2, a3};
    *(f32x4*)(Apos + (f * NH + h) * 32 + kq * 4) = v;
  } else {                                // i / j tables: 4*256*8*8 quads each
    int isI = (id < 98304);
    int rid = id - (isI ? 32768 : 98304);
    int kq = rid & 7, h = (rid >> 3) & 7, m = (rid >> 6) & 255, b = rid >> 14;
    int bidx = bseq[b * SEQ + m], cidx = cseq[b * SEQ + m];
    const float* xb = (isI ? ebi : ebj) + (bidx * NH + h) * 16;
    const float* xc = (isI ? eci : ecj) + (cidx * NH + h) * 16;
    const float* wbB = w1 + (isI ? 32 : 48) * 256 + kq * 32 + h;
    const float* wbC = w1 + (isI ? 64 : 80) * 256 + kq * 32 + h;
#pragma unroll
    for (int j = 0; j < 16; ++j) {
      float xv = xb[j];
      const float* wr = wbB + j * 256;
      a0 += xv * wr[0]; a1 += xv * wr[8]; a2 += xv * wr[16]; a3 += xv * wr[24];
      float yv = xc[j];
      const float* wr2 = wbC + j * 256;
      a0 += yv * wr2[0]; a1 += yv * wr2[8]; a2 += yv * wr2[16]; a3 += yv * wr2[24];
    }
    f32x4 v = {a0, a1, a2, a3};
    float* T = isI ? Ai : Aj;
    *(f32x4*)(T + ((b * SEQ + m) * NH + h) * 32 + kq * 4) = v;
  }
}

// ---------------------------------------------------------------------------
// Kernel 2: main. One wave = (b, h, n-group of 16, m-quarter of 32).
// Per m: build e1-fragment (16 rows=n, K=32) in bf16, one
// mfma_f32_16x16x32_bf16 with A = w2^T (loop-invariant) gives
// D[l, nrow] = e2[nrow, l]; layer-3 = 4 relu*fma + shfl_xor(16)+shfl_xor(32).
// Lanes 0..15 write 16 consecutive outputs (coalesced 64B).
// ---------------------------------------------------------------------------
__global__ __launch_bounds__(256) void dis_att_main(
    const float* __restrict__ attn, const float* __restrict__ w2,
    const float* __restrict__ w3, const float* __restrict__ Apos,
    const float* __restrict__ Ai, const float* __restrict__ Aj,
    float* __restrict__ out) {
  int lane = threadIdx.x & 63;
  int wid = blockIdx.x * 4 + (threadIdx.x >> 6);   // 0..4095
  int mq = wid & 7, ng = (wid >> 3) & 15, h = (wid >> 7) & 7, b = wid >> 10;
  int lcol = lane & 15, kb = lane >> 4, k8 = kb * 8;
  int n = ng * 16 + lcol;

  // Aj contribution: fixed per lane for the whole m-loop
  const float* ajp = Aj + ((b * SEQ + n) * NH + h) * 32 + k8;
  f32x4 aj0 = *(const f32x4*)ajp;
  f32x4 aj1 = *(const f32x4*)(ajp + 4);

  // A-fragment = w2^T : A[i,k] = w2[k][i], lane row i = lcol, k = k8..k8+7
  union { uint32_t u[4]; short8 v; } w2f;
#pragma unroll
  for (int r = 0; r < 4; ++r) {
    float lo = w2[(k8 + 2 * r) * 128 + lcol * 8 + h];
    float hi = w2[(k8 + 2 * r + 1) * 128 + lcol * 8 + h];
    w2f.u[r] = bf16pack2(lo, hi);
  }
  // w3 slice for this lane's 4 D-rows: indices kb*4+r
  float w3v0 = w3[(kb * 4 + 0) * 8 + h];
  float w3v1 = w3[(kb * 4 + 1) * 8 + h];
  float w3v2 = w3[(kb * 4 + 2) * 8 + h];
  float w3v3 = w3[(kb * 4 + 3) * 8 + h];

  const float* aib = Ai + (b * SEQ * NH + h) * 32 + k8;       // + m*256
  const float* apb = Apos + (256 - n) * (NH * 32) + h * 32 + k8; // + m*256
  int obase = ((b * NH + h) * SEQ) * SEQ + ng * 16 + lane;    // + m*SEQ

  int m0 = mq * 32;
#pragma unroll 2
  for (int mi = 0; mi < 32; ++mi) {
    int m = m0 + mi;
    const float* ap = apb + m * (NH * 32);
    f32x4 p0 = *(const f32x4*)ap;
    f32x4 p1 = *(const f32x4*)(ap + 4);
    const float* ai = aib + m * (NH * 32);
    f32x4 i0 = *(const f32x4*)ai;
    f32x4 i1 = *(const f32x4*)(ai + 4);
    f32x4 s0 = p0 + i0 + aj0;
    f32x4 s1 = p1 + i1 + aj1;
    union { uint32_t u[4]; short8 v; } ef;
    ef.u[0] = bf16pack2(fmaxf(s0[0], 0.f), fmaxf(s0[1], 0.f));
    ef.u[1] = bf16pack2(fmaxf(s0[2], 0.f), fmaxf(s0[3], 0.f));
    ef.u[2] = bf16pack2(fmaxf(s1[0], 0.f), fmaxf(s1[1], 0.f));
    ef.u[3] = bf16pack2(fmaxf(s1[2], 0.f), fmaxf(s1[3], 0.f));
    f32x4 c = {0.f, 0.f, 0.f, 0.f};
    f32x4 d = __builtin_amdgcn_mfma_f32_16x16x32_bf16(w2f.v, ef.v, c, 0, 0, 0);
    float part = fmaxf(d[0], 0.f) * w3v0 + fmaxf(d[1], 0.f) * w3v1 +
                 fmaxf(d[2], 0.f) * w3v2 + fmaxf(d[3], 0.f) * w3v3;
    part += __shfl_xor(part, 16, 64);
    part += __shfl_xor(part, 32, 64);
    if (lane < 16) {
      int idx = obase + m * SEQ;
      out[idx] = attn[idx] + part;
    }
  }
}

extern "C" void kernel_launch(void* const* d_in, const int* in_sizes, int n_in,
                              void* d_out, int out_size, void* d_ws, size_t ws_size,
                              hipStream_t stream) {
  const float* attn = (const float*)d_in[0];
  const int* bseq   = (const int*)d_in[1];
  const int* cseq   = (const int*)d_in[2];
  const float* epos = (const float*)d_in[3];
  const float* ebi  = (const float*)d_in[4];
  const float* ebj  = (const float*)d_in[5];
  const float* eci  = (const float*)d_in[6];
  const float* ecj  = (const float*)d_in[7];
  const float* w1   = (const float*)d_in[8];
  const float* w2   = (const float*)d_in[9];
  const float* w3   = (const float*)d_in[10];
  float* out = (float*)d_out;

  float* Apos = (float*)d_ws;            // 512*8*32   = 131072 f32 (512 KB)
  float* Ai   = Apos + 131072;           // 4*256*8*32 = 262144 f32 (1 MB)
  float* Aj   = Ai + 262144;             // 262144 f32 (1 MB)

  hipLaunchKernelGGL(build_tables, dim3(640), dim3(256), 0, stream,
                     bseq, cseq, epos, ebi, ebj, eci, ecj, w1, Apos, Ai, Aj);
  hipLaunchKernelGGL(dis_att_main, dim3(1024), dim3(256), 0, stream,
                     attn, w2, w3, Apos, Ai, Aj, out);
}